// Round 3
// baseline (18217.188 us; speedup 1.0000x reference)
//
#include <hip/hip_runtime.h>

// Network constants (fixed by reference setup)
#define T_STEPS 100
// layers: 2048 -> 2048 -> 2048 -> 512
// Per-layer threads: (fanout/OBLOCK) * BATCH * KSPLIT, OBLOCK=2, KSPLIT=2
#define P0_T 65536    // layer0 (2048 outputs) -> blocks [0,256)
#define P1_T 65536    // layer1 (2048 outputs) -> blocks [256,512)
#define P2_T 16384    // layer2 (512 outputs)  -> blocks [512,576)
#define NTHREADS (P0_T + P1_T + P2_T)   // 147456
#define NBLOCKS  (NTHREADS / 256)       // 576
static_assert(NBLOCKS == 576, "leaf math assumes 576 blocks");
// __launch_bounds__(256,4) caps VGPR at 128 -> >=4 blocks/CU -> capacity
// 1024 >= 576, so a plain launch makes ALL blocks co-resident (persistent).

// ws layout (floats):
//   [0, 393216)        spike buffers: spk0/spk1/spk2, each [2][2048][32]
//   [393216, +2048)    barrier control (u32): 64 leaf ctrs spaced 16,
//                      root at +1024, gen at +1056   (zeroed by memsetAsync)
#define SPK0_OFF 0
#define SPK1_OFF 131072
#define SPK2_OFF 262144
#define CTRL_OFF 393216

// Two-level monotonic grid barrier. k = 1,2,3,... strictly increasing.
// 576 blocks = 64 leaves x 9 blocks. Counters never reset (monotonic):
// leaf target for barrier k is 9k, root target is 64k.
__device__ __forceinline__ void grid_barrier(unsigned* ctrl, unsigned k) {
    __syncthreads();   // all waves' stores drained (vmcnt) before arrival
    if (threadIdx.x == 0) {
        unsigned* leaf = ctrl + (blockIdx.x & 63) * 16;   // 64B spacing
        unsigned* root = ctrl + 1024;
        unsigned* gen  = ctrl + 1056;
        // acq_rel at agent scope: releases this XCD's L2 (spike stores) to LLC
        unsigned p = __hip_atomic_fetch_add(leaf, 1u, __ATOMIC_ACQ_REL,
                                            __HIP_MEMORY_SCOPE_AGENT);
        if (p == 9u * k - 1u) {          // last arrival in this leaf
            unsigned q = __hip_atomic_fetch_add(root, 1u, __ATOMIC_ACQ_REL,
                                                __HIP_MEMORY_SCOPE_AGENT);
            if (q == 64u * k - 1u) {     // last leaf -> open the gate
                __hip_atomic_store(gen, k, __ATOMIC_RELEASE,
                                   __HIP_MEMORY_SCOPE_AGENT);
            }
        }
        // relaxed polling (LLC read, no cache-invalidate storm) ...
        while (__hip_atomic_load(gen, __ATOMIC_RELAXED,
                                 __HIP_MEMORY_SCOPE_AGENT) < k) {
            __builtin_amdgcn_s_sleep(2);
        }
        // ... then one acquire to invalidate stale L1/L2 lines before reads
        (void)__hip_atomic_load(gen, __ATOMIC_ACQUIRE,
                                __HIP_MEMORY_SCOPE_AGENT);
    }
    __syncthreads();
}

__global__ __launch_bounds__(256, 4) void snn_pipeline_kernel(
    const float* __restrict__ x, const float* __restrict__ noise,
    const float* __restrict__ W0, const float* __restrict__ b0,
    const float* __restrict__ W1, const float* __restrict__ b1,
    const float* __restrict__ W2, const float* __restrict__ b2,
    float* __restrict__ out, float* __restrict__ ws)
{
    const int g = blockIdx.x * blockDim.x + threadIdx.x;
    unsigned* ctrl = (unsigned*)(ws + CTRL_OFF);

    // --- partition: layer this thread serves ---
    int part, i;
    if (g < P0_T)            { part = 0; i = g; }
    else if (g < P0_T+P1_T)  { part = 1; i = g - P0_T; }
    else                     { part = 2; i = g - (P0_T+P1_T); }

    const int q  = i & 1;        // K-half (j in [1024q, 1024q+1024))
    const int r  = i >> 1;
    const int b  = r & 31;       // batch index
    const int og = r >> 5;       // o-pair index
    const int o0 = og * 2;

    float* spk0 = ws + SPK0_OFF;
    float* spk1 = ws + SPK1_OFF;
    float* spk2 = ws + SPK2_OFF;

    const float* Wp; const float* bp; float* inb; float* outb;
    if (part == 0)      { Wp = W0; bp = b0; inb = spk0; outb = spk1; }
    else if (part == 1) { Wp = W1; bp = b1; inb = spk1; outb = spk2; }
    else                { Wp = W2; bp = b2; inb = spk2; outb = nullptr; }

    const int jbase = q * 1024;
    const float* __restrict__ w0p = Wp + (size_t)o0 * 2048 + jbase;
    const float* __restrict__ w1p = w0p + 2048;
    const float4* __restrict__ w0v = (const float4*)w0p;  // 4KB-aligned
    const float4* __restrict__ w1v = (const float4*)w1p;

    // LIF state lives in registers of the owner lane (q==0)
    float mem0 = 0.f, mem1 = 0.f, syn0 = 0.f, syn1 = 0.f;
    float osum0 = 0.f, osum1 = 0.f;   // layer-2 spike sums (output)
    float cnt = 0.f;                  // spike count accumulator

    if (g == 0) out[16384] = 0.0f;    // zero total_spikes slot (d_out poisoned);
                                      // flushed to LLC by block0's barrier-1 release

    // Pipelined stages: layer l handles t = s - l
    for (int s = -1; s <= 101; ++s) {
        // --- Poisson encode input spikes for t' = s+1 (part-2 threads) ---
        if (part == 2) {
            const int tp = s + 1;
            if (tp >= 0 && tp < T_STEPS) {
                float* dst = spk0 + (tp & 1) * 65536;
                const float* nz = noise + (size_t)tp * 65536;
                #pragma unroll
                for (int k = 0; k < 4; ++k) {
                    const int m = i + k * P2_T;       // m in [0, 65536)
                    float rate = x[m];
                    rate = fminf(fmaxf(rate, 0.0f), 1.0f);
                    const float sp = (nz[m] < rate) ? 1.0f : 0.0f;
                    const int bb = m >> 11, jj = m & 2047;
                    dst[jj * 32 + bb] = sp;           // transposed [feature][batch]
                }
            }
        }

        const int t = s - part;
        if (t >= 0 && t < T_STEPS) {
            // dot-product half: acc over j in [jbase, jbase+1024)
            const float* __restrict__ st = inb + (t & 1) * 65536 + jbase * 32 + b;
            float a0 = 0.f, a1 = 0.f;
            #pragma unroll 2
            for (int c = 0; c < 256; ++c) {
                const float4 wa = w0v[c];
                const float4 wb = w1v[c];
                const float s0v = st[(4*c + 0) * 32];
                const float s1v = st[(4*c + 1) * 32];
                const float s2v = st[(4*c + 2) * 32];
                const float s3v = st[(4*c + 3) * 32];
                a0 += s0v * wa.x + s1v * wa.y + s2v * wa.z + s3v * wa.w;
                a1 += s0v * wb.x + s1v * wb.y + s2v * wb.z + s3v * wb.w;
            }
            // reduce the 2 K-halves (lanes q=0/1 are adjacent)
            a0 += __shfl_xor(a0, 1);
            a1 += __shfl_xor(a1, 1);

            if (q == 0) {
                const float bias0 = bp[o0], bias1 = bp[o0 + 1];
                // neuron o0:  syn = syn*(1-1/5) + I ; mem = mem*(1-1/20) + syn
                const float I0 = a0 + bias0;
                syn0 = syn0 + (-syn0 / 5.0f + I0);
                mem0 = mem0 + (-mem0 / 20.0f + syn0);
                const float s0 = (mem0 >= 1.0f) ? 1.0f : 0.0f;
                mem0 = (s0 != 0.0f) ? 0.0f : mem0;        // reset
                mem0 = (mem0 > 0.0f) ? mem0 : 0.0f;       // clamp negatives
                // neuron o0+1
                const float I1 = a1 + bias1;
                syn1 = syn1 + (-syn1 / 5.0f + I1);
                mem1 = mem1 + (-mem1 / 20.0f + syn1);
                const float s1 = (mem1 >= 1.0f) ? 1.0f : 0.0f;
                mem1 = (s1 != 0.0f) ? 0.0f : mem1;
                mem1 = (mem1 > 0.0f) ? mem1 : 0.0f;

                cnt += s0 + s1;
                if (part < 2) {
                    float* ob = outb + (t & 1) * 65536;   // consumer reads parity t&1
                    ob[(size_t)o0 * 32 + b]       = s0;
                    ob[(size_t)(o0 + 1) * 32 + b] = s1;
                } else {
                    osum0 += s0; osum1 += s1;
                }
            }
        }
        grid_barrier(ctrl, (unsigned)(s + 2));   // k = 1..103
    }

    // --- epilogue (after final barrier; all spike data settled) ---
    if (part == 2 && q == 0) {
        out[b * 512 + o0]     = osum0 / 100.0f;   // mean over T
        out[b * 512 + o0 + 1] = osum1 / 100.0f;
    }
    // total spike count: wave reduce -> block reduce -> one atomic per WG
    float c = cnt;
    #pragma unroll
    for (int m = 1; m < 64; m <<= 1) c += __shfl_xor(c, m);
    __shared__ float red[4];
    const int lane = threadIdx.x & 63, wv = threadIdx.x >> 6;
    if (lane == 0) red[wv] = c;
    __syncthreads();
    if (threadIdx.x == 0)
        atomicAdd(&out[16384], red[0] + red[1] + red[2] + red[3]);
}

extern "C" void kernel_launch(void* const* d_in, const int* in_sizes, int n_in,
                              void* d_out, int out_size, void* d_ws, size_t ws_size,
                              hipStream_t stream) {
    // setup_inputs() dict order: x, noise, time_steps, W0, b0, W1, b1, W2, b2
    const float* x     = (const float*)d_in[0];
    const float* noise = (const float*)d_in[1];
    // d_in[2] = time_steps (int scalar) — fixed at 100
    const float* W0 = (const float*)d_in[3];
    const float* b0 = (const float*)d_in[4];
    const float* W1 = (const float*)d_in[5];
    const float* b1 = (const float*)d_in[6];
    const float* W2 = (const float*)d_in[7];
    const float* b2 = (const float*)d_in[8];
    float* out = (float*)d_out;
    float* ws  = (float*)d_ws;

    // zero the barrier control block (d_ws is poisoned 0xAA before every call)
    hipMemsetAsync((void*)(ws + CTRL_OFF), 0, 8192, stream);

    snn_pipeline_kernel<<<dim3(NBLOCKS), dim3(256), 0, stream>>>(
        x, noise, W0, b0, W1, b1, W2, b2, out, ws);

    (void)in_sizes; (void)n_in; (void)out_size; (void)ws_size;
}

// Round 5
// 6221.087 us; speedup vs baseline: 2.9283x; 2.9283x over previous
//
#include <hip/hip_runtime.h>

// Network constants (fixed by reference setup)
#define T_STEPS 100
// layers: 2048 -> 2048 -> 2048 -> 512
// Per-layer threads: (fanout/OBLOCK) * 32batch * KSPLIT(2), OBLOCK=2
#define P0_T 65536    // layer0 (2048 outputs) -> blocks [0,256)
#define P1_T 65536    // layer1 (2048 outputs) -> blocks [256,512)
#define P2_T 16384    // layer2 (512 outputs)  -> blocks [512,576)
#define NTHREADS (P0_T + P1_T + P2_T)   // 147456
#define NBLOCKS  (NTHREADS / 256)       // 576
static_assert(NBLOCKS == 576, "barrier leaf math assumes 576 blocks");
// LDS: 8 rows x 2048 fp16 = 32KB/block -> 4 blocks/CU (132KB<160KB), and
// __launch_bounds__(256,4) caps VGPR at 128 -> capacity 1024 >= 576: all
// blocks co-resident, persistent-kernel barrier is safe.

// ws layout (BYTES):
//   [0, 786432)           spike buffers (fp16): spk0/spk1/spk2, each [2][32][2048]
//   [786432, +8192)       barrier control (u32): 64 leaf ctrs spaced 16 words,
//                         root at word+1024, gen at word+1056 (memsetAsync zeroed)
#define SPK_HALFS   131072          // halves per buffer ([2][32][2048])
#define CTRL_OFF_B  786432

typedef _Float16 half2_t __attribute__((ext_vector_type(2)));
typedef _Float16 half8_t __attribute__((ext_vector_type(8)));

#if defined(__has_builtin) && __has_builtin(__builtin_amdgcn_fdot2)
__device__ __forceinline__ float dot8(half8_t s, half8_t w, float acc) {
    acc = __builtin_amdgcn_fdot2(__builtin_shufflevector(s, s, 0, 1),
                                 __builtin_shufflevector(w, w, 0, 1), acc, false);
    acc = __builtin_amdgcn_fdot2(__builtin_shufflevector(s, s, 2, 3),
                                 __builtin_shufflevector(w, w, 2, 3), acc, false);
    acc = __builtin_amdgcn_fdot2(__builtin_shufflevector(s, s, 4, 5),
                                 __builtin_shufflevector(w, w, 4, 5), acc, false);
    acc = __builtin_amdgcn_fdot2(__builtin_shufflevector(s, s, 6, 7),
                                 __builtin_shufflevector(w, w, 6, 7), acc, false);
    return acc;
}
#else
__device__ __forceinline__ float dot8(half8_t s, half8_t w, float acc) {
    #pragma unroll
    for (int e = 0; e < 8; ++e) acc += (float)s[e] * (float)w[e];
    return acc;
}
#endif

// Two-level monotonic grid barrier. k = 1,2,3,... strictly increasing.
// 576 blocks = 64 leaves x 9. Counters never reset: leaf target 9k, root 64k.
__device__ __forceinline__ void grid_barrier(unsigned* ctrl, unsigned k) {
    __syncthreads();
    if (threadIdx.x == 0) {
        unsigned* leaf = ctrl + (blockIdx.x & 63) * 16;   // 64B spacing
        unsigned* root = ctrl + 1024;
        unsigned* gen  = ctrl + 1056;
        unsigned p = __hip_atomic_fetch_add(leaf, 1u, __ATOMIC_ACQ_REL,
                                            __HIP_MEMORY_SCOPE_AGENT);
        if (p == 9u * k - 1u) {
            unsigned q = __hip_atomic_fetch_add(root, 1u, __ATOMIC_ACQ_REL,
                                                __HIP_MEMORY_SCOPE_AGENT);
            if (q == 64u * k - 1u) {
                __hip_atomic_store(gen, k, __ATOMIC_RELEASE,
                                   __HIP_MEMORY_SCOPE_AGENT);
            }
        }
        while (__hip_atomic_load(gen, __ATOMIC_RELAXED,
                                 __HIP_MEMORY_SCOPE_AGENT) < k) {
            __builtin_amdgcn_s_sleep(2);
        }
        (void)__hip_atomic_load(gen, __ATOMIC_ACQUIRE,
                                __HIP_MEMORY_SCOPE_AGENT);
    }
    __syncthreads();
}

__global__ __launch_bounds__(256, 4) void snn_pipeline_kernel(
    const float* __restrict__ x, const float* __restrict__ noise,
    const float* __restrict__ W0, const float* __restrict__ b0,
    const float* __restrict__ W1, const float* __restrict__ b1,
    const float* __restrict__ W2, const float* __restrict__ b2,
    float* __restrict__ out, float* __restrict__ ws)
{
    const int g = blockIdx.x * blockDim.x + threadIdx.x;
    unsigned* ctrl = (unsigned*)((char*)ws + CTRL_OFF_B);

    // --- partition: layer this thread serves (partitions are block-aligned) ---
    int part, i;
    if (g < P0_T)            { part = 0; i = g; }
    else if (g < P0_T+P1_T)  { part = 1; i = g - P0_T; }
    else                     { part = 2; i = g - (P0_T+P1_T); }

    const int q  = i & 1;        // K-half (features [1024q, 1024q+1024))
    const int r  = i >> 1;
    const int b  = r & 31;       // batch index
    const int og = r >> 5;       // global o-pair index
    const int o0 = og * 2;

    _Float16* spk0 = (_Float16*)ws;           // input spikes   [2][32][2048]
    _Float16* spk1 = spk0 + SPK_HALFS;        // layer0 outputs [2][32][2048]
    _Float16* spk2 = spk1 + SPK_HALFS;        // layer1 outputs [2][32][2048]

    const float* Wp; const float* bp; const _Float16* inb; _Float16* outb;
    if (part == 0)      { Wp = W0; bp = b0; inb = spk0; outb = spk1; }
    else if (part == 1) { Wp = W1; bp = b1; inb = spk1; outb = spk2; }
    else                { Wp = W2; bp = b2; inb = spk2; outb = nullptr; }

    // --- stage this block's 8 weight rows into LDS as fp16 (read HBM once) ---
    const int i_base   = i - threadIdx.x;       // block-local partition offset
    const int row_base = i_base >> 5;           // first output row of this block
    __shared__ _Float16 wlds[8 * 2048];         // 32KB, broadcast reads (no pad)
    {
        const float4* __restrict__ wsrc =
            (const float4*)(Wp + (size_t)row_base * 2048);   // 8KB-aligned
        half2_t* __restrict__ wdst = (half2_t*)wlds;
        #pragma unroll
        for (int v = threadIdx.x; v < 4096; v += 256) {      // 8*2048/4 float4s
            const float4 w = wsrc[v];
            half2_t h0 = {(_Float16)w.x, (_Float16)w.y};
            half2_t h1 = {(_Float16)w.z, (_Float16)w.w};
            wdst[2*v]     = h0;
            wdst[2*v + 1] = h1;
        }
    }
    __syncthreads();

    const int o0_local = o0 - row_base;         // 0,2,4,6
    const int jbase    = q * 1024;
    const half8_t* __restrict__ wv0 =
        (const half8_t*)(wlds + (size_t)o0_local * 2048 + jbase);
    const half8_t* __restrict__ wv1 =
        (const half8_t*)(wlds + (size_t)(o0_local + 1) * 2048 + jbase);

    // LIF state lives in registers of the owner lane (q==0)
    float mem0 = 0.f, mem1 = 0.f, syn0 = 0.f, syn1 = 0.f;
    float osum0 = 0.f, osum1 = 0.f;   // layer-2 spike sums (output)
    float cnt = 0.f;                  // total spike count accumulator

    if (g == 0) out[16384] = 0.0f;    // zero total_spikes slot (d_out poisoned)

    // Pipelined stages: layer l handles t = s - l
    for (int s = -1; s <= 101; ++s) {
        // --- Poisson encode input spikes for t' = s+1 (part-2 threads) ---
        if (part == 2) {
            const int tp = s + 1;
            if (tp >= 0 && tp < T_STEPS) {
                _Float16* dst = spk0 + (tp & 1) * 65536;     // [32][2048] fp16
                const float* nz = noise + (size_t)tp * 65536;
                #pragma unroll
                for (int k = 0; k < 4; ++k) {
                    const int m = i + k * P2_T;              // m in [0, 65536)
                    float rate = x[m];
                    rate = fminf(fmaxf(rate, 0.0f), 1.0f);
                    const float sp = (nz[m] < rate) ? 1.0f : 0.0f;
                    // layout [b][j]: m = b*2048 + j already matches
                    dst[m] = (_Float16)sp;
                }
            }
        }

        const int t = s - part;
        if (t >= 0 && t < T_STEPS) {
            // dot-product half: features [jbase, jbase+1024), spikes [b][j] fp16
            const half8_t* __restrict__ sp8 =
                (const half8_t*)(inb + (t & 1) * 65536 + (size_t)b * 2048 + jbase);
            float a0e = 0.f, a0o = 0.f, a1e = 0.f, a1o = 0.f;  // 4 chains
            #pragma unroll 2
            for (int c = 0; c < 128; c += 2) {
                const half8_t s0 = sp8[c];
                const half8_t s1 = sp8[c + 1];
                a0e = dot8(s0, wv0[c],     a0e);
                a0o = dot8(s1, wv0[c + 1], a0o);
                a1e = dot8(s0, wv1[c],     a1e);
                a1o = dot8(s1, wv1[c + 1], a1o);
            }
            float a0 = a0e + a0o, a1 = a1e + a1o;
            // reduce the 2 K-halves (lanes q=0/1 adjacent, same og,b)
            a0 += __shfl_xor(a0, 1);
            a1 += __shfl_xor(a1, 1);

            if (q == 0) {
                const float bias0 = bp[o0], bias1 = bp[o0 + 1];
                // syn += -syn/5 + I ; mem += -mem/20 + syn  (dt=1)
                const float I0 = a0 + bias0;
                syn0 = syn0 + (-syn0 / 5.0f + I0);
                mem0 = mem0 + (-mem0 / 20.0f + syn0);
                const float s0 = (mem0 >= 1.0f) ? 1.0f : 0.0f;
                mem0 = (s0 != 0.0f) ? 0.0f : mem0;        // reset
                mem0 = (mem0 > 0.0f) ? mem0 : 0.0f;       // clamp negatives
                const float I1 = a1 + bias1;
                syn1 = syn1 + (-syn1 / 5.0f + I1);
                mem1 = mem1 + (-mem1 / 20.0f + syn1);
                const float s1 = (mem1 >= 1.0f) ? 1.0f : 0.0f;
                mem1 = (s1 != 0.0f) ? 0.0f : mem1;
                mem1 = (mem1 > 0.0f) ? mem1 : 0.0f;

                cnt += s0 + s1;
                if (part < 2) {
                    // one packed 4B store: spikes for (o0, o0+1) at batch b
                    half2_t pair = {(_Float16)s0, (_Float16)s1};
                    *(half2_t*)(outb + (t & 1) * 65536 + (size_t)b * 2048 + o0) = pair;
                } else {
                    osum0 += s0; osum1 += s1;
                }
            }
        }
        grid_barrier(ctrl, (unsigned)(s + 2));   // k = 1..103
    }

    // --- epilogue (after final barrier) ---
    if (part == 2 && q == 0) {
        out[b * 512 + o0]     = osum0 / 100.0f;   // mean over T
        out[b * 512 + o0 + 1] = osum1 / 100.0f;
    }
    // total spike count: wave reduce -> block reduce -> one atomic per WG
    float c = cnt;
    #pragma unroll
    for (int m = 1; m < 64; m <<= 1) c += __shfl_xor(c, m);
    __shared__ float red[4];
    const int lane = threadIdx.x & 63, wv = threadIdx.x >> 6;
    if (lane == 0) red[wv] = c;
    __syncthreads();
    if (threadIdx.x == 0)
        atomicAdd(&out[16384], red[0] + red[1] + red[2] + red[3]);
}

extern "C" void kernel_launch(void* const* d_in, const int* in_sizes, int n_in,
                              void* d_out, int out_size, void* d_ws, size_t ws_size,
                              hipStream_t stream) {
    // setup_inputs() dict order: x, noise, time_steps, W0, b0, W1, b1, W2, b2
    const float* x     = (const float*)d_in[0];
    const float* noise = (const float*)d_in[1];
    // d_in[2] = time_steps (int scalar) — fixed at 100
    const float* W0 = (const float*)d_in[3];
    const float* b0 = (const float*)d_in[4];
    const float* W1 = (const float*)d_in[5];
    const float* b1 = (const float*)d_in[6];
    const float* W2 = (const float*)d_in[7];
    const float* b2 = (const float*)d_in[8];
    float* out = (float*)d_out;
    float* ws  = (float*)d_ws;

    // zero the barrier control block (d_ws is poisoned 0xAA before every call)
    (void)hipMemsetAsync((void*)((char*)d_ws + CTRL_OFF_B), 0, 8192, stream);

    snn_pipeline_kernel<<<dim3(NBLOCKS), dim3(256), 0, stream>>>(
        x, noise, W0, b0, W1, b1, W2, b2, out, ws);

    (void)in_sizes; (void)n_in; (void)out_size; (void)ws_size;
}

// Round 6
// 1479.549 us; speedup vs baseline: 12.3127x; 4.2047x over previous
//
#include <hip/hip_runtime.h>

// SNN: 3 layers (2048->2048->2048->512), T=100, batch 32, LIF dynamics.
// Persistent kernel, pipeline-skewed layers, MFMA 16x16x32 f16.
//
// Block roles (288 blocks x 256 thr = 4 waves):
//   [0,128)   layer0, rows blk*16         (W0: 2048x2048)
//   [128,256) layer1, rows (blk-128)*16   (W1: 2048x2048)
//   [256,288) layer2, rows (blk-256)*16   (W2: 512x2048) + Poisson encoder
// Each block owns a 16-row x 32-batch output tile; 4 waves = 4-way K-split
// (512 features each); wave w covers 2 N-tiles (batch 0-15,16-31).
// LDS: weights in A-frag swizzle 64KB + 6KB reduction = 70KB -> 2 blocks/CU
// -> capacity 512 >= 288: all blocks co-resident (persistent barrier safe).
#define T_STEPS 100
#define NBLOCKS 288

typedef _Float16 half8_t __attribute__((ext_vector_type(8)));
typedef _Float16 half4_t __attribute__((ext_vector_type(4)));
typedef float    f32x4  __attribute__((ext_vector_type(4)));

// ws offsets in HALVES (spike buffers), bytes for ctrl.
// Spike buffer layout (per interface, per parity): B-frag blocked:
//   half_idx(k,b) = ((k>>5)*2 + (b>>4))*512 + ((k>>3)&3)*128 + (b&15)*8 + (k&7)
// so a wave's b128 load at ((kbg*2+nt)*512 + lane*8) yields
//   B[k = kbg*32 + (lane>>4)*8 + j][n = nt*16 + (lane&15)].
#define IN_OFF  0          // input spikes  [2 parity][65536]
#define S1_OFF  131072     // layer0 -> layer1
#define S2_OFF  262144     // layer1 -> layer2
#define CTRL_OFF_B 786432  // barrier control (8KB, memsetAsync-zeroed)

// Two-level monotonic grid barrier: 288 = 32 leaves x 9 blocks.
__device__ __forceinline__ void grid_barrier(unsigned* ctrl, unsigned k) {
    __syncthreads();
    if (threadIdx.x == 0) {
        unsigned* leaf = ctrl + (blockIdx.x & 31) * 16;   // 64B spacing
        unsigned* root = ctrl + 1024;
        unsigned* gen  = ctrl + 1056;
        unsigned p = __hip_atomic_fetch_add(leaf, 1u, __ATOMIC_ACQ_REL,
                                            __HIP_MEMORY_SCOPE_AGENT);
        if (p == 9u * k - 1u) {
            unsigned q = __hip_atomic_fetch_add(root, 1u, __ATOMIC_ACQ_REL,
                                                __HIP_MEMORY_SCOPE_AGENT);
            if (q == 32u * k - 1u)
                __hip_atomic_store(gen, k, __ATOMIC_RELEASE,
                                   __HIP_MEMORY_SCOPE_AGENT);
        }
        while (__hip_atomic_load(gen, __ATOMIC_RELAXED,
                                 __HIP_MEMORY_SCOPE_AGENT) < k)
            __builtin_amdgcn_s_sleep(2);
        (void)__hip_atomic_load(gen, __ATOMIC_ACQUIRE,
                                __HIP_MEMORY_SCOPE_AGENT);
    }
    __syncthreads();
}

__global__ __launch_bounds__(256, 2) void snn_mfma_kernel(
    const float* __restrict__ x, const float* __restrict__ noise,
    const float* __restrict__ W0, const float* __restrict__ b0,
    const float* __restrict__ W1, const float* __restrict__ b1,
    const float* __restrict__ W2, const float* __restrict__ b2,
    float* __restrict__ out, float* __restrict__ ws)
{
    const int blk  = blockIdx.x;
    const int tid  = threadIdx.x;
    const int w    = tid >> 6;          // wave 0..3 = K-chunk
    const int lane = tid & 63;
    const int quad = lane >> 4;         // k-octet / row-group
    const int mi   = lane & 15;

    unsigned* ctrl = (unsigned*)((char*)ws + CTRL_OFF_B);
    _Float16* wsh  = (_Float16*)ws;

    int layer, row_base;
    if (blk < 128)      { layer = 0; row_base = blk * 16; }
    else if (blk < 256) { layer = 1; row_base = (blk - 128) * 16; }
    else                { layer = 2; row_base = (blk - 256) * 16; }

    const float* Wp = (layer == 0) ? W0 : (layer == 1) ? W1 : W2;
    const float* bp = (layer == 0) ? b0 : (layer == 1) ? b1 : b2;
    const _Float16* inbuf = wsh + ((layer == 0) ? IN_OFF : (layer == 1) ? S1_OFF : S2_OFF);
    _Float16* outbuf = (layer == 0) ? (wsh + S1_OFF) : (layer == 1) ? (wsh + S2_OFF) : nullptr;

    // ---- stage weights into LDS, A-frag blocked: wlds[e*8+j] with
    //      e = w*1024 + kb*64 + quad*16 + m  <->  W[row_base+m][w*512+kb*32+quad*8+j]
    __shared__ _Float16 wlds[16 * 2048];      // 64 KB
    __shared__ float    redf[3 * 2 * 64 * 4]; // 6 KB K-split reduction
    #pragma unroll
    for (int it = 0; it < 16; ++it) {
        const int e  = tid + it * 256;        // [0,4096)
        const int m  = e & 15;
        const int k0 = (e >> 4) * 8;          // w*512 + kb*32 + quad*8
        const float4 f1 = *(const float4*)(Wp + (size_t)(row_base + m) * 2048 + k0);
        const float4 f2 = *(const float4*)(Wp + (size_t)(row_base + m) * 2048 + k0 + 4);
        half8_t h = {(_Float16)f1.x, (_Float16)f1.y, (_Float16)f1.z, (_Float16)f1.w,
                     (_Float16)f2.x, (_Float16)f2.y, (_Float16)f2.z, (_Float16)f2.w};
        *(half8_t*)(wlds + (size_t)e * 8) = h;
    }
    __syncthreads();

    // bias for this lane's 4 C-rows (wave0 is the LIF owner)
    float bias[4];
    #pragma unroll
    for (int r = 0; r < 4; ++r) bias[r] = bp[row_base + quad * 4 + r];

    // encoder state (layer-2 blocks double as Poisson encoders)
    float rate[8];
    int enc_b = 0, enc_k0 = 0;
    if (layer == 2) {
        const int ei = (blk - 256) * 256 + tid;   // [0,8192)
        enc_b  = ei >> 8;                         // batch
        enc_k0 = (ei & 255) * 8;                  // 8 features
        const float4 x1 = *(const float4*)(x + enc_b * 2048 + enc_k0);
        const float4 x2 = *(const float4*)(x + enc_b * 2048 + enc_k0 + 4);
        rate[0]=x1.x; rate[1]=x1.y; rate[2]=x1.z; rate[3]=x1.w;
        rate[4]=x2.x; rate[5]=x2.y; rate[6]=x2.z; rate[7]=x2.w;
        #pragma unroll
        for (int j = 0; j < 8; ++j) rate[j] = fminf(fmaxf(rate[j], 0.0f), 1.0f);
    }

    // LIF state (wave0 lanes): 2 N-tiles x 4 rows
    float mem[2][4] = {{0,0,0,0},{0,0,0,0}};
    float syn[2][4] = {{0,0,0,0},{0,0,0,0}};
    float osum[2][4] = {{0,0,0,0},{0,0,0,0}};
    float cnt = 0.f;

    if (blk == 0 && tid == 0) out[16384] = 0.0f;  // total_spikes slot

    for (int s = -1; s <= 101; ++s) {
        // ---- Poisson encode t' = s+1 (layer-2 blocks, all waves) ----
        if (layer == 2) {
            const int tp = s + 1;
            if (tp >= 0 && tp < T_STEPS) {
                const float4 n1 = *(const float4*)(noise + (size_t)tp * 65536 + enc_b * 2048 + enc_k0);
                const float4 n2 = *(const float4*)(noise + (size_t)tp * 65536 + enc_b * 2048 + enc_k0 + 4);
                const float nz[8] = {n1.x,n1.y,n1.z,n1.w,n2.x,n2.y,n2.z,n2.w};
                half8_t sp;
                #pragma unroll
                for (int j = 0; j < 8; ++j)
                    sp[j] = (nz[j] < rate[j]) ? (_Float16)1.0f : (_Float16)0.0f;
                const int idx = (((enc_k0 >> 5) * 2 + (enc_b >> 4)) * 512)
                              + ((enc_k0 >> 3) & 3) * 128 + (enc_b & 15) * 8;
                *(half8_t*)(wsh + IN_OFF + (tp & 1) * 65536 + idx) = sp;
            }
        }

        const int t = s - layer;
        if (t >= 0 && t < T_STEPS) {
            const _Float16* sin = inbuf + (t & 1) * 65536;
            f32x4 acc0 = {0,0,0,0}, acc1 = {0,0,0,0};
            // 16 K-steps of 32: A from LDS (conflict-free b128),
            // B from global (wave-contiguous 1KB per load)
            #pragma unroll
            for (int kb = 0; kb < 16; ++kb) {
                const half8_t a = *(const half8_t*)(wlds + ((w * 16 + kb) * 64 + lane) * 8);
                const int kbg = w * 16 + kb;
                const half8_t bfr0 = *(const half8_t*)(sin + (kbg * 2 + 0) * 512 + lane * 8);
                const half8_t bfr1 = *(const half8_t*)(sin + (kbg * 2 + 1) * 512 + lane * 8);
                acc0 = __builtin_amdgcn_mfma_f32_16x16x32_f16(a, bfr0, acc0, 0, 0, 0);
                acc1 = __builtin_amdgcn_mfma_f32_16x16x32_f16(a, bfr1, acc1, 0, 0, 0);
            }
            // ---- K-split reduction via LDS (waves 1..3 -> wave 0) ----
            if (w > 0) {
                *(f32x4*)(redf + (((w - 1) * 2 + 0) * 64 + lane) * 4) = acc0;
                *(f32x4*)(redf + (((w - 1) * 2 + 1) * 64 + lane) * 4) = acc1;
            }
            __syncthreads();
            if (w == 0) {
                #pragma unroll
                for (int wv = 0; wv < 3; ++wv) {
                    acc0 += *(const f32x4*)(redf + ((wv * 2 + 0) * 64 + lane) * 4);
                    acc1 += *(const f32x4*)(redf + ((wv * 2 + 1) * 64 + lane) * 4);
                }
                // ---- LIF for 8 neurons: (nt, reg); C: row=quad*4+reg, col=mi
                #pragma unroll
                for (int nt = 0; nt < 2; ++nt) {
                    const f32x4 a = nt ? acc1 : acc0;
                    half4_t pk;
                    #pragma unroll
                    for (int r = 0; r < 4; ++r) {
                        const float I = a[r] + bias[r];
                        syn[nt][r] = syn[nt][r] + (-syn[nt][r] / 5.0f + I);
                        mem[nt][r] = mem[nt][r] + (-mem[nt][r] / 20.0f + syn[nt][r]);
                        const float sv = (mem[nt][r] >= 1.0f) ? 1.0f : 0.0f;
                        mem[nt][r] = (sv != 0.0f) ? 0.0f : mem[nt][r];
                        mem[nt][r] = (mem[nt][r] > 0.0f) ? mem[nt][r] : 0.0f;
                        cnt += sv;
                        pk[r] = (_Float16)sv;
                        osum[nt][r] += sv;       // only used by layer 2
                    }
                    if (layer < 2) {
                        // C-layout -> B-frag layout: one coalesced 8B store
                        const int o_eb = row_base + quad * 4;
                        const int idx = (((o_eb >> 5) * 2 + nt) * 64
                                         + ((o_eb >> 3) & 3) * 16 + mi) * 8 + (o_eb & 7);
                        *(half4_t*)(outbuf + (t & 1) * 65536 + idx) = pk;
                    }
                }
            }
        }
        grid_barrier(ctrl, (unsigned)(s + 2));   // k = 1..103
    }

    // ---- epilogue ----
    if (layer == 2 && w == 0) {
        #pragma unroll
        for (int nt = 0; nt < 2; ++nt)
            #pragma unroll
            for (int r = 0; r < 4; ++r)
                out[(nt * 16 + mi) * 512 + row_base + quad * 4 + r] = osum[nt][r] / 100.0f;
    }
    // total spikes: wave reduce -> block reduce -> one atomic per block
    float c = cnt;
    #pragma unroll
    for (int m = 1; m < 64; m <<= 1) c += __shfl_xor(c, m);
    __shared__ float red4[4];
    if (lane == 0) red4[w] = c;
    __syncthreads();
    if (tid == 0)
        atomicAdd(&out[16384], red4[0] + red4[1] + red4[2] + red4[3]);
}

extern "C" void kernel_launch(void* const* d_in, const int* in_sizes, int n_in,
                              void* d_out, int out_size, void* d_ws, size_t ws_size,
                              hipStream_t stream) {
    // setup_inputs() dict order: x, noise, time_steps, W0, b0, W1, b1, W2, b2
    const float* x     = (const float*)d_in[0];
    const float* noise = (const float*)d_in[1];
    const float* W0 = (const float*)d_in[3];
    const float* b0 = (const float*)d_in[4];
    const float* W1 = (const float*)d_in[5];
    const float* b1 = (const float*)d_in[6];
    const float* W2 = (const float*)d_in[7];
    const float* b2 = (const float*)d_in[8];
    float* out = (float*)d_out;
    float* ws  = (float*)d_ws;

    // zero barrier control (d_ws is poisoned 0xAA before every call)
    (void)hipMemsetAsync((void*)((char*)d_ws + CTRL_OFF_B), 0, 8192, stream);

    snn_mfma_kernel<<<dim3(NBLOCKS), dim3(256), 0, stream>>>(
        x, noise, W0, b0, W1, b1, W2, b2, out, ws);

    (void)in_sizes; (void)n_in; (void)out_size; (void)ws_size;
}